// Round 1
// baseline (835.030 us; speedup 1.0000x reference)
//
#include <hip/hip_runtime.h>

// LinearTrajectoryAttention, restructured:
//   Qphi = phi(query @ Wq^T + bq)                  [16][16][64]
//   w[b,h,t] = Qphi[b,h,:] . phi(key_t @ Wk^T + bk)[h]   (fused into K-proj epilogue)
//   den[b,h] = sum_t w ;  S[b,h,:] = sum_t w * value_t
//   pre[b,h*64+e] = (Wv[h*64+e,:].S + den*bv) / (den + 1e-6)
//   out = pre @ Wo^T + bo
// Only K-projection is a big GEMM (275 GF, bf16 MFMA). V-proj/KV einsum eliminated.

typedef __attribute__((ext_vector_type(8))) short  bf16x8;
typedef __attribute__((ext_vector_type(4))) short  bf16x4;
typedef __attribute__((ext_vector_type(4))) float  f32x4;

// workspace layout (bytes)
#define WS_QPHI 0u          // [16][16][64] f32      = 65536
#define WS_PRE  65536u      // [16][1024]  f32       = 65536
#define WS_S    131072u     // [16][16][1024] f32    = 1048576
#define WS_WKB  1179648u    // [1024][1024] bf16     = 2097152
#define WS_W    3276800u    // [16][16][8192] f32    = 8388608  (total ~11.7 MB)

__device__ __forceinline__ unsigned short f2bf(float f) {
  union { float f; unsigned u; } c; c.f = f;
  unsigned u = c.u;
  return (unsigned short)((u + 0x7fffu + ((u >> 16) & 1u)) >> 16);  // RNE
}

__device__ __forceinline__ void gload_lds16(const void* g, void* l) {
  __builtin_amdgcn_global_load_lds((const __attribute__((address_space(1))) void*)g,
                                   (__attribute__((address_space(3))) void*)l, 16, 0, 0);
}

// ---- Wk fp32 -> bf16 ----------------------------------------------------
__global__ void k_convert_wk(const float* __restrict__ Wk, unsigned short* __restrict__ Wkb) {
  int i = blockIdx.x * 256 + threadIdx.x;     // 262144 float4s
  f32x4 v = ((const f32x4*)Wk)[i];
  bf16x4 o;
  o[0] = (short)f2bf(v[0]); o[1] = (short)f2bf(v[1]);
  o[2] = (short)f2bf(v[2]); o[3] = (short)f2bf(v[3]);
  ((bf16x4*)Wkb)[i] = o;
}

// ---- Q projection + feature map ----------------------------------------
__global__ void k_qproj(const float* __restrict__ q, const float* __restrict__ Wq,
                        const float* __restrict__ bq, float* __restrict__ Qphi) {
  int b = blockIdx.x, h = blockIdx.y, d = threadIdx.x;  // block = 64
  const f32x4* qr = (const f32x4*)(q + b * 1024);
  const f32x4* wr = (const f32x4*)(Wq + (size_t)(h * 64 + d) * 1024);
  float s = bq[h * 64 + d];
  for (int i = 0; i < 256; ++i) {
    f32x4 a = qr[i], ww = wr[i];
    s += a[0]*ww[0] + a[1]*ww[1] + a[2]*ww[2] + a[3]*ww[3];
  }
  s = s > 0.f ? s + 1.f : __expf(s);  // elu(x)+1
  Qphi[(b * 16 + h) * 64 + d] = s;
}

// ---- K projection GEMM (BM=128, BN=256=4 heads, BK=32) + fused w epilogue
__global__ __launch_bounds__(512)
void k_kproj(const float* __restrict__ key, const unsigned short* __restrict__ Wkb,
             const float* __restrict__ bk, const float* __restrict__ Qphi,
             float* __restrict__ w) {
  __shared__ unsigned short sA[2][128 * 40];   // padded pitch 40 shorts (80 B) -> 2-way free
  __shared__ unsigned short sB[2][256 * 32];   // linear (global_load_lds dest)
  const int np   = blockIdx.x;                 // 0..3  (4 heads each)
  const int mb   = blockIdx.y;                 // 0..1023
  const int b    = mb >> 6;
  const int mrow = (mb & 63) << 7;
  const int tid  = threadIdx.x;
  const int lane = tid & 63;
  const int wv   = tid >> 6;                   // 8 waves, 2 (rows) x 4 (cols)
  const int wr   = wv >> 2;
  const int wc   = wv & 3;
  const int n0   = np << 8;
  const int h    = (np << 2) | wc;             // this wave's head
  const int l15  = lane & 15;
  const int lk   = (lane >> 4) << 3;           // k-offset 0,8,16,24

  // A staging map: thread -> (row = tid/4, 8 floats at col (tid&3)*8)
  const int ar = tid >> 2, aq = tid & 3;
  const float* Ab = key + ((size_t)((b << 13) + mrow + ar)) * 1024 + aq * 8;
  const int sAoff = ar * 40 + aq * 8;

  // B staging map (global_load_lds, 2 calls of 16 B per thread)
  const unsigned short* Bb = Wkb + ((size_t)(n0 + (wv << 5) + (lane >> 2))) * 1024
                                 + ((lane & 3) << 3);

  f32x4 acc[4][4];
  #pragma unroll
  for (int i = 0; i < 4; ++i)
    #pragma unroll
    for (int j = 0; j < 4; ++j) acc[i][j] = (f32x4)0.f;

  float qreg[4];
  #pragma unroll
  for (int ni = 0; ni < 4; ++ni)
    qreg[ni] = Qphi[((b << 4) + h) * 64 + ni * 16 + l15];

  // prologue: stage chunk 0
  f32x4 p0 = *(const f32x4*)(Ab);
  f32x4 p1 = *(const f32x4*)(Ab + 4);
  gload_lds16(Bb,             &sB[0][wv * 1024]);
  gload_lds16(Bb + 16 * 1024, &sB[0][wv * 1024 + 512]);
  {
    bf16x8 v;
    v[0]=(short)f2bf(p0[0]); v[1]=(short)f2bf(p0[1]); v[2]=(short)f2bf(p0[2]); v[3]=(short)f2bf(p0[3]);
    v[4]=(short)f2bf(p1[0]); v[5]=(short)f2bf(p1[1]); v[6]=(short)f2bf(p1[2]); v[7]=(short)f2bf(p1[3]);
    *(bf16x8*)&sA[0][sAoff] = v;
  }
  __syncthreads();

  for (int t = 0; t < 32; ++t) {
    const int cur = t & 1, nxt = cur ^ 1;
    f32x4 a0, a1;
    if (t < 31) {                               // prefetch chunk t+1
      const float* An = Ab + (t + 1) * 32;
      a0 = *(const f32x4*)(An);
      a1 = *(const f32x4*)(An + 4);
      const unsigned short* Bn = Bb + (t + 1) * 32;
      gload_lds16(Bn,             &sB[nxt][wv * 1024]);
      gload_lds16(Bn + 16 * 1024, &sB[nxt][wv * 1024 + 512]);
    }
    bf16x8 af[4], bfr[4];
    #pragma unroll
    for (int mi = 0; mi < 4; ++mi)
      af[mi] = *(const bf16x8*)&sA[cur][((wr << 6) + mi * 16 + l15) * 40 + lk];
    #pragma unroll
    for (int ni = 0; ni < 4; ++ni)
      bfr[ni] = *(const bf16x8*)&sB[cur][((wc << 6) + ni * 16 + l15) * 32 + lk];
    #pragma unroll
    for (int mi = 0; mi < 4; ++mi)
      #pragma unroll
      for (int ni = 0; ni < 4; ++ni)
        acc[mi][ni] = __builtin_amdgcn_mfma_f32_16x16x32_bf16(af[mi], bfr[ni], acc[mi][ni], 0, 0, 0);
    if (t < 31) {
      bf16x8 v;
      v[0]=(short)f2bf(a0[0]); v[1]=(short)f2bf(a0[1]); v[2]=(short)f2bf(a0[2]); v[3]=(short)f2bf(a0[3]);
      v[4]=(short)f2bf(a1[0]); v[5]=(short)f2bf(a1[1]); v[6]=(short)f2bf(a1[2]); v[7]=(short)f2bf(a1[3]);
      *(bf16x8*)&sA[nxt][sAoff] = v;
    }
    __syncthreads();
  }

  // epilogue: bias + phi + dot with Qphi -> w[b,h,t]
  float bias[4];
  #pragma unroll
  for (int ni = 0; ni < 4; ++ni) bias[ni] = bk[n0 + (wc << 6) + ni * 16 + l15];

  #pragma unroll
  for (int mi = 0; mi < 4; ++mi) {
    float wa[4];
    #pragma unroll
    for (int r = 0; r < 4; ++r) {
      float s = 0.f;
      #pragma unroll
      for (int ni = 0; ni < 4; ++ni) {
        float x = acc[mi][ni][r] + bias[ni];
        x = x > 0.f ? x + 1.f : __expf(x);     // phi
        s += x * qreg[ni];
      }
      wa[r] = s;
    }
    #pragma unroll
    for (int m = 1; m < 16; m <<= 1)
      #pragma unroll
      for (int r = 0; r < 4; ++r) wa[r] += __shfl_xor(wa[r], m, 64);
    if (l15 == 0) {
      const int rg = lane >> 4;
      #pragma unroll
      for (int r = 0; r < 4; ++r) {
        int trow = mrow + (wr << 6) + mi * 16 + (rg << 2) + r;
        w[(((size_t)((b << 4) + h)) << 13) + trow] = wa[r];
      }
    }
  }
}

// ---- S[b,h,:] = sum_t w * value_t  (fp32, streaming) --------------------
__global__ __launch_bounds__(256)
void k_sgemm(const float* __restrict__ value, const float* __restrict__ w,
             float* __restrict__ S) {
  __shared__ float wl[16 * 128];
  const int b = blockIdx.x, tc = blockIdx.y;   // 16 x 64
  const int t0 = tc << 7;
  const int tid = threadIdx.x;
  for (int i = tid; i < 16 * 128; i += 256)
    wl[i] = w[(((size_t)(b * 16 + (i >> 7))) << 13) + t0 + (i & 127)];
  __syncthreads();
  f32x4 acc[16];
  #pragma unroll
  for (int h = 0; h < 16; ++h) acc[h] = (f32x4)0.f;
  const f32x4* vb = (const f32x4*)(value + ((size_t)(b << 13) + t0) * 1024) + tid;
  #pragma unroll 4
  for (int t = 0; t < 128; ++t) {
    f32x4 x = vb[t << 8];
    #pragma unroll
    for (int h = 0; h < 16; ++h)
      acc[h] += x * wl[(h << 7) + t];
  }
  #pragma unroll
  for (int h = 0; h < 16; ++h) {
    float* sp = S + ((b << 4) + h) * 1024 + (tid << 2);
    atomicAdd(sp + 0, acc[h][0]); atomicAdd(sp + 1, acc[h][1]);
    atomicAdd(sp + 2, acc[h][2]); atomicAdd(sp + 3, acc[h][3]);
  }
}

// ---- den + num + divide --------------------------------------------------
__global__ void k_numden(const float* __restrict__ w, const float* __restrict__ S,
                         const float* __restrict__ Wv, const float* __restrict__ bv,
                         float* __restrict__ pre) {
  const int b = blockIdx.x, h = blockIdx.y, e = threadIdx.x;  // block = 64
  const float* wb = w + (((size_t)(b * 16 + h)) << 13);
  float dsum = 0.f;
  for (int i = 0; i < 128; ++i) dsum += wb[i * 64 + e];
  #pragma unroll
  for (int m = 1; m < 64; m <<= 1) dsum += __shfl_xor(dsum, m, 64);
  const f32x4* sr  = (const f32x4*)(S + (b * 16 + h) * 1024);
  const f32x4* wvr = (const f32x4*)(Wv + (size_t)(h * 64 + e) * 1024);
  float ns = 0.f;
  for (int i = 0; i < 256; ++i) {
    f32x4 a = sr[i], c = wvr[i];
    ns += a[0]*c[0] + a[1]*c[1] + a[2]*c[2] + a[3]*c[3];
  }
  ns += dsum * bv[h * 64 + e];
  pre[b * 1024 + h * 64 + e] = ns / (dsum + 1e-6f);
}

// ---- output projection ---------------------------------------------------
__global__ __launch_bounds__(256)
void k_outproj(const float* __restrict__ pre, const float* __restrict__ Wo,
               const float* __restrict__ bo, float* __restrict__ out) {
  __shared__ float pl[1024];
  const int b = blockIdx.x, ch = blockIdx.y;   // 16 x 4
  const int tid = threadIdx.x, lane = tid & 63, wv = tid >> 6;
  for (int i = tid; i < 1024; i += 256) pl[i] = pre[b * 1024 + i];
  __syncthreads();
  for (int oi = 0; oi < 64; ++oi) {
    int o = (ch << 8) + (wv << 6) + oi;
    const f32x4* wrow = (const f32x4*)(Wo + (size_t)o * 1024);
    float s = 0.f;
    #pragma unroll
    for (int j = 0; j < 4; ++j) {
      f32x4 v = wrow[lane * 4 + j];
      f32x4 p = *(const f32x4*)&pl[(lane * 4 + j) * 4];
      s += v[0]*p[0] + v[1]*p[1] + v[2]*p[2] + v[3]*p[3];
    }
    #pragma unroll
    for (int m = 1; m < 64; m <<= 1) s += __shfl_xor(s, m, 64);
    if (lane == 0) out[b * 1024 + o] = s + bo[o];
  }
}

extern "C" void kernel_launch(void* const* d_in, const int* in_sizes, int n_in,
                              void* d_out, int out_size, void* d_ws, size_t ws_size,
                              hipStream_t stream) {
  const float* query = (const float*)d_in[0];
  const float* key   = (const float*)d_in[1];
  const float* value = (const float*)d_in[2];
  const float* Wq    = (const float*)d_in[3];
  const float* bq    = (const float*)d_in[4];
  const float* Wk    = (const float*)d_in[5];
  const float* bk    = (const float*)d_in[6];
  const float* Wv    = (const float*)d_in[7];
  const float* bv    = (const float*)d_in[8];
  const float* Wo    = (const float*)d_in[9];
  const float* bo    = (const float*)d_in[10];
  float* out = (float*)d_out;
  char* ws = (char*)d_ws;
  float*          Qphi = (float*)(ws + WS_QPHI);
  float*          pre  = (float*)(ws + WS_PRE);
  float*          S    = (float*)(ws + WS_S);
  unsigned short* Wkb  = (unsigned short*)(ws + WS_WKB);
  float*          w    = (float*)(ws + WS_W);

  hipMemsetAsync(S, 0, 16 * 16 * 1024 * sizeof(float), stream);
  k_convert_wk<<<1024, 256, 0, stream>>>(Wk, Wkb);
  k_qproj<<<dim3(16, 16), 64, 0, stream>>>(query, Wq, bq, Qphi);
  k_kproj<<<dim3(4, 1024), 512, 0, stream>>>(key, Wkb, bk, Qphi, w);
  k_sgemm<<<dim3(16, 64), 256, 0, stream>>>(value, w, S);
  k_numden<<<dim3(16, 16), 64, 0, stream>>>(w, S, Wv, bv, pre);
  k_outproj<<<dim3(16, 4), 256, 0, stream>>>(pre, Wo, bo, out);
}